// Round 1
// baseline (700.123 us; speedup 1.0000x reference)
//
#include <hip/hip_runtime.h>

// Adding-doubling radiative transfer: B=2048 cols, N=60 layers, C=128 channels.
// One thread per (b,c) column; all layer recurrences serial per thread,
// fully unrolled so rs[]/rt[]/absD[] live in registers.

#define NL 60
#define CC 128

__global__ __launch_bounds__(256) void adding_doubling_kernel(
    const float* __restrict__ a, const float* __restrict__ r,
    const float* __restrict__ t, const float* __restrict__ s,
    float* __restrict__ flux_down, float* __restrict__ flux_up,
    float* __restrict__ absorbed, int ncol)
{
    const int tid = blockIdx.x * blockDim.x + threadIdx.x;
    if (tid >= ncol) return;
    const int b = tid >> 7;          // tid / CC
    const int c = tid & (CC - 1);    // tid % CC
    const int base = b * NL * CC + c;   // element (b, l=0, c); layer l at base + l*CC

    // ---------------- Phase A: bottom-up cumulative surface reflection ----
    // rs[n-1] = r[n-1]; for l=n-2..0: dd = 1/(1-rs[l+1]*r[l]);
    // rs[l] = r[l] + rs[l+1]*t[l]^2*dd.   (ds[l] = dd recomputed later)
    float rs[NL];
    {
        rs[NL - 1] = r[base + (NL - 1) * CC];
        #pragma unroll
        for (int l = NL - 2; l >= 0; --l) {
            float rl = r[base + l * CC];
            float tl = t[base + l * CC];
            float dd = 1.0f / (1.0f - rs[l + 1] * rl);
            rs[l] = rl + rs[l + 1] * tl * tl * dd;
        }
    }

    // ---------------- Phase B: forward pass ------------------------------
    // Simultaneously: top-down cumulative reflection rt[] (+ dt on the fly),
    // downward flux scan, flux_down writes, absorbed_down into absD[] regs.
    float rt[NL - 1];     // rt[0..NL-2]
    float absD[NL - 1];   // absD[1..NL-2] used
    {
        float r_prev = r[base];        // r[m-1]
        float s_prev = s[base];        // s[m-1]
        float ds_prev = 1.0f / (1.0f - rs[1] * r_prev);   // ds[0]
        float rt_prev = r_prev;        // rt[0]
        rt[0] = r_prev;
        float flux = 0.0f;
        #pragma unroll
        for (int m = 1; m < NL; ++m) {
            float rm = r[base + m * CC];
            float sm = s[base + m * CC];
            float tm = t[base + m * CC];
            float am = a[base + m * CC];
            // downward flux: add s_down[m-1] = (s[m-1] + s[m]*r[m-1]) * ds[m-1]
            flux += (s_prev + sm * r_prev) * ds_prev;
            flux_down[base + m * CC] = flux;
            if (m < NL - 1) {
                float ds_m = 1.0f / (1.0f - rs[m + 1] * rm);
                absD[m] = am * (1.0f + rs[m + 1] * tm * ds_m) * flux;
                flux *= tm * ds_m;
                ds_prev = ds_m;
            } else {
                // layer n-1: absorbed_up is 0 there, write final absorbed now
                absorbed[base + m * CC] = am * flux;
            }
            // top-down reflection recurrence
            float dt_m = 1.0f / (1.0f - rt_prev * rm);
            float rt_m = rm + rt_prev * tm * tm * dt_m;
            if (m < NL - 1) rt[m] = rt_m;
            rt_prev = rt_m;
            r_prev = rm;
            s_prev = sm;
        }
        flux_down[base] = 0.0f;   // flux_down[0] = 0
    }

    // ---------------- Phase C: reverse pass (upward flux) -----------------
    // dt[l] = 1/(1 - rt[l-1]*r[l]) recomputed from rt[] and r.
    // s_up[l] = (s[l] + s[l-1]*r[l]) * dt[l]  (l >= 1);  s_up[0] = s[0].
    {
        float flux = 0.0f;
        float r_hi = r[base + (NL - 1) * CC];   // r[k+2]
        float s_hi = s[base + (NL - 1) * CC];   // s[k+2]
        float dt_hi = 1.0f / (1.0f - rt[NL - 2] * r_hi);   // dt[k+2]
        #pragma unroll
        for (int k = NL - 3; k >= 0; --k) {
            float r1 = r[base + (k + 1) * CC];
            float s1 = s[base + (k + 1) * CC];
            float t1 = t[base + (k + 1) * CC];
            float a1 = a[base + (k + 1) * CC];
            // flux += s_up[k+2]
            flux += (s_hi + s1 * r_hi) * dt_hi;
            flux_up[base + (k + 2) * CC] = flux;
            float dt1 = 1.0f / (1.0f - rt[k] * r1);   // dt[k+1]
            absorbed[base + (k + 1) * CC] =
                absD[k + 1] + flux * a1 * (1.0f + t1 * rt[k] * dt1);
            flux *= t1 * dt1;
            r_hi = r1;
            s_hi = s1;
            dt_hi = dt1;
        }
        // tail: after k=0 iter, r_hi=r[1], s_hi=s[1], dt_hi=dt[1]
        float r0v = r[base];
        float s0v = s[base];
        float t0v = t[base];
        float a0v = a[base];
        float flux1 = flux + (s_hi + s0v * r_hi) * dt_hi;   // + s_up[1]
        flux_up[base + CC] = flux1;
        absorbed[base] = flux1 * a0v;                        // abs1 (absD[0]=0)
        flux_up[base] = flux1 * t0v + s0v;                   // flux1*t[0] + s_up[0]
    }
}

extern "C" void kernel_launch(void* const* d_in, const int* in_sizes, int n_in,
                              void* d_out, int out_size, void* d_ws, size_t ws_size,
                              hipStream_t stream) {
    const float* a = (const float*)d_in[0];
    const float* r = (const float*)d_in[1];
    const float* t = (const float*)d_in[2];
    const float* s = (const float*)d_in[3];
    const int total = in_sizes[0];       // B*N*C
    const int ncol = total / NL;         // B*C columns
    float* flux_down = (float*)d_out;
    float* flux_up = flux_down + total;
    float* absorbed = flux_up + total;
    const int threads = 256;
    const int blocks = (ncol + threads - 1) / threads;
    adding_doubling_kernel<<<blocks, threads, 0, stream>>>(
        a, r, t, s, flux_down, flux_up, absorbed, ncol);
}